// Round 14
// baseline (52.917 us; speedup 1.0000x reference)
//
#include <hip/hip_runtime.h>
#include <hip/hip_bf16.h>

#define NUM_NODES 100000
#define BATCH 4096
#define NNB 64
#define HID 128
#define NHEAD 8
#define HDIM 16
#define TDIM 64
#define RDIM 64
#define START_TC 0.2f
#define END_TC 0.8f
#define NORMS 0.25f

typedef __attribute__((ext_vector_type(4))) float f32x4;
typedef __attribute__((ext_vector_type(2))) float f32x2;
typedef __attribute__((ext_vector_type(8))) short bf16x8;

#define AST 136   // A-tile row stride in shorts (272B: 16B-aligned rows)
#define KST 130   // K tile row stride in shorts (260B)
#define APAD 10   // attn_t row stride in floats

__device__ __forceinline__ short fb(float f) {
    __hip_bfloat16 h = __float2bfloat16(f);
    return *reinterpret_cast<short*>(&h);
}

// Pack weights into MFMA B-fragment order with INTERLEAVED column ownership:
// fragment position (nt, lane d) holds physical col (nt>>1)*32 + 2*d + (nt&1),
// so after the GEMM each lane's two cols per window are ADJACENT (2d, 2d+1).
__global__ void prep_kernel(const float* __restrict__ t2v_w, const float* __restrict__ t2v_b,
                            const float* __restrict__ tW_k, const float* __restrict__ tb_k,
                            const float* __restrict__ tW_q, const float* __restrict__ tb_q,
                            const float* __restrict__ tW_v, const float* __restrict__ tb_v,
                            const float* __restrict__ rW_k, const float* __restrict__ rb_k,
                            const float* __restrict__ rW_v, const float* __restrict__ rb_v,
                            short* __restrict__ wfrag, float* __restrict__ bias_kv,
                            float* __restrict__ q0_add)
{
    int blk = blockIdx.x, t = threadIdx.x;
    if (blk < 128) {
        int idx = blk * 256 + t;
        int i   = idx & 7;
        int ln  = (idx >> 3) & 63;
        int nt  = (idx >> 9) & 15;
        int kt  = idx >> 13;
        int k = kt * 32 + (ln >> 4) * 8 + i;
        int c = (nt >> 1) * 32 + 2 * (ln & 15) + (nt & 1);   // interleaved col
        int cc = (c < HID) ? c : c - HID;
        float val;
        if (k < TDIM) val = (c < HID) ? tW_k[k*HID + cc] : tW_v[k*HID + cc];
        else          val = (c < HID) ? rW_k[(k-TDIM)*HID + cc] : rW_v[(k-TDIM)*HID + cc];
        wfrag[idx] = fb(val);
    } else if (blk == 128) {
        bias_kv[t] = (t < HID) ? (tb_k[t] + rb_k[t]) : (tb_v[t-HID] + rb_v[t-HID]);
    } else if (t < HID) {
        float s = tb_q[t];
        for (int j = 0; j < TDIM; ++j) {
            float f = START_TC * t2v_w[j] + t2v_b[j];
            float tv = (j == 0) ? f : __sinf(f);
            s += tv * tW_q[j*HID + t];
        }
        q0_add[t] = s;
    }
}

// 512 threads = 8 waves. R13 + interleaved cols: phase-3 gathers are f32x2
// (16 loads/thread instead of 32, half the address math), Ksh writes pack to
// u32, out stores are f32x2. Same bytes, same granules, fewer instructions.
__launch_bounds__(512, 6)
__global__ void aggr_kernel(const float* __restrict__ k_tab, const float* __restrict__ q_tab,
                            const float* __restrict__ v_tab,
                            const int* __restrict__ nid, const int* __restrict__ neighbors,
                            const float* __restrict__ times, const float* __restrict__ rels,
                            const float* __restrict__ t2v_w, const float* __restrict__ t2v_b,
                            const short* __restrict__ wfrag, const float* __restrict__ bias_kv,
                            const float* __restrict__ q0_add, float* __restrict__ out)
{
    __shared__ __align__(16) short AK[64 * AST];
    __shared__ __align__(16) float q_lds[HID];
    __shared__ float maskadd[NNB];
    __shared__ int   nb_lds[NNB];     // masked entries forced to 0 (dummy row)
    __shared__ __align__(16) float attn_t[NNB][APAD];
    __shared__ int   anyvalid;

    short* A   = AK;   // stride AST, phases 1-2
    short* Ksh = AK;   // stride KST, phases 3-4

    const int b = blockIdx.x;
    const int t = threadIdx.x;
    const int w = t >> 6;   // wave 0..7
    const int l = t & 63;   // lane
    const int d = l & 15;   // position within 16-lane group

    // ---- prefetch: B-fragments for this wave's GEMM columns ----
    const bf16x8* wf = (const bf16x8*)wfrag;
    bf16x8 bfr[4][2];
    #pragma unroll
    for (int kt = 0; kt < 4; ++kt)
        #pragma unroll
        for (int j = 0; j < 2; ++j)
            bfr[kt][j] = wf[(kt*16 + (2*w + j))*64 + l];

    // ---- phase 0: neighbors / mask / q ----
    if (t < 64) {
        float tt = times[b*NNB + t];
        bool valid = (tt >= START_TC) && (tt < END_TC);
        nb_lds[t] = valid ? neighbors[b*NNB + t] : 0;
        maskadd[t] = valid ? 0.f : -1e30f;
        unsigned long long bal = __ballot(valid);
        if (t == 0) anyvalid = (bal != 0ull) ? 1 : 0;
    } else if (t < 96) {
        int i = t - 64;
        int q_node = nid[b];
        f32x4 qa = *(const f32x4*)(q_tab + (size_t)q_node*HID + i*4);
        f32x4 qb = *(const f32x4*)(q0_add + i*4);
        *(f32x4*)(q_lds + i*4) = qa + qb;
    }

    // ---- phase 1: stage A-tile = [t2v(times) | rels], wave-specialized ----
    if (w < 4) {
        float tt = times[b*NNB + l];
        int c0 = w * 16;
        bf16x8 v0, v1;
        #pragma unroll
        for (int u = 0; u < 8; ++u) {
            int j = c0 + u;
            float f = fmaf(tt, t2v_w[j], t2v_b[j]);
            v0[u] = fb((j == 0) ? f : __sinf(f));
        }
        #pragma unroll
        for (int u = 0; u < 8; ++u) {
            int j = c0 + 8 + u;
            float f = fmaf(tt, t2v_w[j], t2v_b[j]);
            v1[u] = fb(__sinf(f));
        }
        *(bf16x8*)(&A[l*AST + c0])     = v0;
        *(bf16x8*)(&A[l*AST + c0 + 8]) = v1;
    } else {
        int s = w - 4;
        float tt = times[b*NNB + l];
        bool valid = (tt >= START_TC) && (tt < END_TC);
        int lrow = valid ? l : 0;
        const float* rp = rels + ((size_t)b*NNB + lrow)*RDIM + s*16;
        f32x4 r0 = *(const f32x4*)(rp);
        f32x4 r1 = *(const f32x4*)(rp + 4);
        f32x4 r2 = *(const f32x4*)(rp + 8);
        f32x4 r3 = *(const f32x4*)(rp + 12);
        bf16x8 o0, o1;
        #pragma unroll
        for (int e = 0; e < 4; ++e) {
            o0[e]   = fb(r0[e]);  o0[e+4] = fb(r1[e]);
            o1[e]   = fb(r2[e]);  o1[e+4] = fb(r3[e]);
        }
        *(bf16x8*)(&A[l*AST + TDIM + s*16])     = o0;
        *(bf16x8*)(&A[l*AST + TDIM + s*16 + 8]) = o1;
    }
    __syncthreads();

    // ---- phase 2: GEMM; wave w owns cols 32w..32w+31 (interleaved per lane) ----
    f32x4 acc[4][2];
    #pragma unroll
    for (int mt = 0; mt < 4; ++mt)
        #pragma unroll
        for (int j = 0; j < 2; ++j)
            acc[mt][j] = (f32x4){0.f, 0.f, 0.f, 0.f};

    #pragma unroll
    for (int kt = 0; kt < 4; ++kt) {
        bf16x8 af[4];
        int kcol = kt*32 + (l >> 4)*8;
        #pragma unroll
        for (int mt = 0; mt < 4; ++mt)
            af[mt] = *(const bf16x8*)(&A[(mt*16 + d)*AST + kcol]);
        #pragma unroll
        for (int mt = 0; mt < 4; ++mt)
            #pragma unroll
            for (int j = 0; j < 2; ++j)
                acc[mt][j] = __builtin_amdgcn_mfma_f32_16x16x32_bf16(af[mt], bfr[kt][j], acc[mt][j], 0, 0, 0);
    }
    __syncthreads();   // A dead; Ksh may overwrite

    // ---- phase 3: gather table rows (f32x2, batched, dummy-predicated) ----
    // lane d owns cols {cw+2d, cw+2d+1}: acc[mt][0]=col 2d, acc[mt][1]=col 2d+1.
    if (w < 4) {
        int cw = w * 32;
        f32x2 biasr = *(const f32x2*)(bias_kv + cw + 2*d);
        #pragma unroll
        for (int mt = 0; mt < 4; ++mt) {
            f32x2 kv[4];
            #pragma unroll
            for (int i = 0; i < 4; ++i) {
                int n = mt*16 + ((l >> 4) << 2) + i;
                kv[i] = *(const f32x2*)(k_tab + (size_t)nb_lds[n]*HID + cw + 2*d);
            }
            #pragma unroll
            for (int i = 0; i < 4; ++i) {
                int n = mt*16 + ((l >> 4) << 2) + i;
                unsigned p0 = (unsigned)(unsigned short)fb(acc[mt][0][i] + biasr[0] + kv[i][0]);
                unsigned p1 = (unsigned)(unsigned short)fb(acc[mt][1][i] + biasr[1] + kv[i][1]);
                *(unsigned*)(&Ksh[n*KST + cw + 2*d]) = p0 | (p1 << 16);
            }
        }
    } else {
        int cw = (w - 4) * 32;
        f32x2 biasr = *(const f32x2*)(bias_kv + HID + cw + 2*d);
        #pragma unroll
        for (int mt = 0; mt < 4; ++mt) {
            f32x2 vv[4];
            #pragma unroll
            for (int i = 0; i < 4; ++i) {
                int n = mt*16 + ((l >> 4) << 2) + i;
                vv[i] = *(const f32x2*)(v_tab + (size_t)nb_lds[n]*HID + cw + 2*d);
            }
            #pragma unroll
            for (int i = 0; i < 4; ++i) {
                acc[mt][0][i] += biasr[0] + vv[i][0];
                acc[mt][1][i] += biasr[1] + vv[i][1];
            }
        }
    }
    __syncthreads();

    // ---- phase 4: scores + softmax. lane l = neighbor l; wave w = head w ----
    {
        const short* krow = &Ksh[l*KST + w*16];
        float s = 0.f;
        #pragma unroll
        for (int e = 0; e < 8; ++e) {
            unsigned u = *(const unsigned*)(&krow[2*e]);
            float k0 = __uint_as_float(u << 16);
            float k1 = __uint_as_float(u & 0xffff0000u);
            s = fmaf(q_lds[w*16 + 2*e],     k0, s);
            s = fmaf(q_lds[w*16 + 2*e + 1], k1, s);
        }
        float sc = s * NORMS + maskadd[l];
        float m = sc;
        #pragma unroll
        for (int off = 1; off <= 32; off <<= 1)
            m = fmaxf(m, __shfl_xor(m, off));
        float e = __expf(sc - m);
        float sum = e;
        #pragma unroll
        for (int off = 1; off <= 32; off <<= 1)
            sum += __shfl_xor(sum, off);
        attn_t[l][w] = e / sum;
    }
    __syncthreads();

    // ---- phase 5: PV (waves 4-7 hold v). Both lane cols share one head. ----
    if (w >= 4) {
        int gq = w - 4;
        int hoff = 2*gq + ((d >= 8) ? 1 : 0);   // head of cols cw+2d, cw+2d+1
        float p0 = 0.f, p1 = 0.f;
        #pragma unroll
        for (int mt = 0; mt < 4; ++mt) {
            #pragma unroll
            for (int i = 0; i < 4; ++i) {
                int n = mt*16 + ((l >> 4) << 2) + i;
                float at = attn_t[n][hoff];
                p0 = fmaf(at, acc[mt][0][i], p0);
                p1 = fmaf(at, acc[mt][1][i], p1);
            }
        }
        p0 += __shfl_xor(p0, 16);  p0 += __shfl_xor(p0, 32);
        p1 += __shfl_xor(p1, 16);  p1 += __shfl_xor(p1, 32);
        if (l < 16) {
            f32x2 st;
            st[0] = anyvalid ? p0 : 0.f;
            st[1] = anyvalid ? p1 : 0.f;
            *(f32x2*)(out + (size_t)b*HID + gq*32 + 2*l) = st;
        }
    }
}

extern "C" void kernel_launch(void* const* d_in, const int* in_sizes, int n_in,
                              void* d_out, int out_size, void* d_ws, size_t ws_size,
                              hipStream_t stream)
{
    const float* k_tab = (const float*)d_in[0];
    const float* q_tab = (const float*)d_in[1];
    const float* v_tab = (const float*)d_in[2];
    const int*   nid   = (const int*)d_in[3];
    const int*   neighbors = (const int*)d_in[4];
    const float* times = (const float*)d_in[5];
    const float* rels  = (const float*)d_in[6];
    const float* t2v_w = (const float*)d_in[7];
    const float* t2v_b = (const float*)d_in[8];
    const float* tW_k  = (const float*)d_in[9];
    const float* tb_k  = (const float*)d_in[10];
    const float* tW_q  = (const float*)d_in[11];
    const float* tb_q  = (const float*)d_in[12];
    const float* tW_v  = (const float*)d_in[13];
    const float* tb_v  = (const float*)d_in[14];
    const float* rW_k  = (const float*)d_in[15];
    const float* rb_k  = (const float*)d_in[16];
    const float* rW_v  = (const float*)d_in[17];
    const float* rb_v  = (const float*)d_in[18];

    short* wfrag   = (short*)d_ws;                          // 32768 bf16 = 64KB
    float* bias_kv = (float*)((char*)d_ws + 65536);         // 256 f32
    float* q0_add  = (float*)((char*)d_ws + 65536 + 1024);  // 128 f32

    prep_kernel<<<130, 256, 0, stream>>>(t2v_w, t2v_b, tW_k, tb_k, tW_q, tb_q,
                                         tW_v, tb_v, rW_k, rb_k, rW_v, rb_v,
                                         wfrag, bias_kv, q0_add);
    aggr_kernel<<<BATCH, 512, 0, stream>>>(k_tab, q_tab, v_tab, nid, neighbors,
                                           times, rels, t2v_w, t2v_b,
                                           wfrag, bias_kv, q0_add, (float*)d_out);
}

// Round 15
// 49.417 us; speedup vs baseline: 1.0708x; 1.0708x over previous
//
#include <hip/hip_runtime.h>
#include <hip/hip_bf16.h>

#define NUM_NODES 100000
#define BATCH 4096
#define NNB 64
#define HID 128
#define NHEAD 8
#define HDIM 16
#define TDIM 64
#define RDIM 64
#define START_TC 0.2f
#define END_TC 0.8f
#define NORMS 0.25f

typedef __attribute__((ext_vector_type(4))) float f32x4;
typedef __attribute__((ext_vector_type(2))) float f32x2;
typedef __attribute__((ext_vector_type(8))) short bf16x8;

#define AST 136   // A-tile row stride in shorts (272B: 16B-aligned rows)
#define KST 130   // K tile row stride in shorts (260B)
#define APAD 10   // attn_t row stride in floats (40B: 8B-aligned f32x2 reads)

__device__ __forceinline__ short fb(float f) {
    __hip_bfloat16 h = __float2bfloat16(f);
    return *reinterpret_cast<short*>(&h);
}

// Pack weights into MFMA B-fragment order, combined biases, and q0 = t_q(START_T).
__global__ void prep_kernel(const float* __restrict__ t2v_w, const float* __restrict__ t2v_b,
                            const float* __restrict__ tW_k, const float* __restrict__ tb_k,
                            const float* __restrict__ tW_q, const float* __restrict__ tb_q,
                            const float* __restrict__ tW_v, const float* __restrict__ tb_v,
                            const float* __restrict__ rW_k, const float* __restrict__ rb_k,
                            const float* __restrict__ rW_v, const float* __restrict__ rb_v,
                            short* __restrict__ wfrag, float* __restrict__ bias_kv,
                            float* __restrict__ q0_add)
{
    int blk = blockIdx.x, t = threadIdx.x;
    if (blk < 128) {
        int idx = blk * 256 + t;
        int i   = idx & 7;
        int ln  = (idx >> 3) & 63;
        int nt  = (idx >> 9) & 15;
        int kt  = idx >> 13;
        int k = kt * 32 + (ln >> 4) * 8 + i;
        int c = nt * 16 + (ln & 15);
        int cc = (c < HID) ? c : c - HID;
        float val;
        if (k < TDIM) val = (c < HID) ? tW_k[k*HID + cc] : tW_v[k*HID + cc];
        else          val = (c < HID) ? rW_k[(k-TDIM)*HID + cc] : rW_v[(k-TDIM)*HID + cc];
        wfrag[idx] = fb(val);
    } else if (blk == 128) {
        bias_kv[t] = (t < HID) ? (tb_k[t] + rb_k[t]) : (tb_v[t-HID] + rb_v[t-HID]);
    } else if (t < HID) {
        float s = tb_q[t];
        for (int j = 0; j < TDIM; ++j) {
            float f = START_TC * t2v_w[j] + t2v_b[j];
            float tv = (j == 0) ? f : __sinf(f);
            s += tv * tW_q[j*HID + t];
        }
        q0_add[t] = s;
    }
}

// 512 threads = 8 waves. R12 structure + predicated rels stream:
// masked rows (~40%) redirect BOTH their k/v gather and their rels stream to
// hot dummy lines -- loads stay batched/coalesced, random granules vanish
// from the L2-miss/L3 path. Masked garbage is annihilated by the -1e30 mask
// (exp -> exactly 0) resp. x0 attention weight.
__launch_bounds__(512, 6)
__global__ void aggr_kernel(const float* __restrict__ k_tab, const float* __restrict__ q_tab,
                            const float* __restrict__ v_tab,
                            const int* __restrict__ nid, const int* __restrict__ neighbors,
                            const float* __restrict__ times, const float* __restrict__ rels,
                            const float* __restrict__ t2v_w, const float* __restrict__ t2v_b,
                            const short* __restrict__ wfrag, const float* __restrict__ bias_kv,
                            const float* __restrict__ q0_add, float* __restrict__ out)
{
    __shared__ __align__(16) short AK[64 * AST];
    __shared__ __align__(16) float q_lds[HID];
    __shared__ float maskadd[NNB];
    __shared__ int   nb_lds[NNB];     // masked entries forced to 0 (dummy row)
    __shared__ __align__(16) float attn_t[NNB][APAD];
    __shared__ int   anyvalid;

    short* A   = AK;   // stride AST, phases 1-2
    short* Ksh = AK;   // stride KST, phases 3-4

    const int b = blockIdx.x;
    const int t = threadIdx.x;
    const int w = t >> 6;   // wave 0..7
    const int l = t & 63;   // lane

    // ---- prefetch: B-fragments for this wave's GEMM columns ----
    const bf16x8* wf = (const bf16x8*)wfrag;
    bf16x8 bfr[4][2];
    #pragma unroll
    for (int kt = 0; kt < 4; ++kt)
        #pragma unroll
        for (int j = 0; j < 2; ++j)
            bfr[kt][j] = wf[(kt*16 + (2*w + j))*64 + l];

    // ---- phase 0: neighbors / mask / q ----
    if (t < 64) {
        float tt = times[b*NNB + t];
        bool valid = (tt >= START_TC) && (tt < END_TC);
        // predication at the source: masked neighbors gather table row 0
        nb_lds[t] = valid ? neighbors[b*NNB + t] : 0;
        maskadd[t] = valid ? 0.f : -1e30f;
        unsigned long long bal = __ballot(valid);
        if (t == 0) anyvalid = (bal != 0ull) ? 1 : 0;
    } else if (t < 96) {
        int i = t - 64;
        int q_node = nid[b];
        f32x4 qa = *(const f32x4*)(q_tab + (size_t)q_node*HID + i*4);
        f32x4 qb = *(const f32x4*)(q0_add + i*4);
        *(f32x4*)(q_lds + i*4) = qa + qb;
    }

    // ---- phase 1: stage A-tile = [t2v(times) | rels], wave-specialized ----
    if (w < 4) {
        float tt = times[b*NNB + l];
        int c0 = w * 16;
        bf16x8 v0, v1;
        #pragma unroll
        for (int u = 0; u < 8; ++u) {
            int j = c0 + u;
            float f = fmaf(tt, t2v_w[j], t2v_b[j]);
            v0[u] = fb((j == 0) ? f : __sinf(f));
        }
        #pragma unroll
        for (int u = 0; u < 8; ++u) {
            int j = c0 + 8 + u;
            float f = fmaf(tt, t2v_w[j], t2v_b[j]);
            v1[u] = fb(__sinf(f));
        }
        *(bf16x8*)(&A[l*AST + c0])     = v0;
        *(bf16x8*)(&A[l*AST + c0 + 8]) = v1;
    } else {
        int s = w - 4;
        // predicated rels stream: masked rows read the block's row-0 line (hot)
        float tt = times[b*NNB + l];
        bool valid = (tt >= START_TC) && (tt < END_TC);
        int lrow = valid ? l : 0;
        const float* rp = rels + ((size_t)b*NNB + lrow)*RDIM + s*16;
        f32x4 r0 = *(const f32x4*)(rp);
        f32x4 r1 = *(const f32x4*)(rp + 4);
        f32x4 r2 = *(const f32x4*)(rp + 8);
        f32x4 r3 = *(const f32x4*)(rp + 12);
        bf16x8 o0, o1;
        #pragma unroll
        for (int e = 0; e < 4; ++e) {
            o0[e]   = fb(r0[e]);  o0[e+4] = fb(r1[e]);
            o1[e]   = fb(r2[e]);  o1[e+4] = fb(r3[e]);
        }
        *(bf16x8*)(&A[l*AST + TDIM + s*16])     = o0;
        *(bf16x8*)(&A[l*AST + TDIM + s*16 + 8]) = o1;
    }
    __syncthreads();

    // ---- phase 2: GEMM [64x128] @ [128x256]; wave w owns cols 32w..32w+31 ----
    f32x4 acc[4][2];
    #pragma unroll
    for (int mt = 0; mt < 4; ++mt)
        #pragma unroll
        for (int j = 0; j < 2; ++j)
            acc[mt][j] = (f32x4){0.f, 0.f, 0.f, 0.f};

    #pragma unroll
    for (int kt = 0; kt < 4; ++kt) {
        bf16x8 af[4];
        int kcol = kt*32 + (l >> 4)*8;
        #pragma unroll
        for (int mt = 0; mt < 4; ++mt)
            af[mt] = *(const bf16x8*)(&A[(mt*16 + (l & 15))*AST + kcol]);
        #pragma unroll
        for (int mt = 0; mt < 4; ++mt)
            #pragma unroll
            for (int j = 0; j < 2; ++j)
                acc[mt][j] = __builtin_amdgcn_mfma_f32_16x16x32_bf16(af[mt], bfr[kt][j], acc[mt][j], 0, 0, 0);
    }
    __syncthreads();   // A dead; Ksh may overwrite

    // ---- phase 3: gather table rows (batched, branch-free, dummy-predicated) ----
    if (w < 4) {
        int cw = w * 32;
        float biasr[2];
        #pragma unroll
        for (int j = 0; j < 2; ++j)
            biasr[j] = bias_kv[cw + j*16 + (l & 15)];
        #pragma unroll
        for (int mt = 0; mt < 4; ++mt) {
            float k0v[4], k1v[4];
            #pragma unroll
            for (int i = 0; i < 4; ++i) {
                int n = mt*16 + ((l >> 4) << 2) + i;
                const float* trow = k_tab + (size_t)nb_lds[n]*HID + cw + (l & 15);
                k0v[i] = trow[0];
                k1v[i] = trow[16];
            }
            #pragma unroll
            for (int i = 0; i < 4; ++i) {
                int n = mt*16 + ((l >> 4) << 2) + i;
                Ksh[n*KST + cw +      (l & 15)] = fb(acc[mt][0][i] + biasr[0] + k0v[i]);
                Ksh[n*KST + cw + 16 + (l & 15)] = fb(acc[mt][1][i] + biasr[1] + k1v[i]);
            }
        }
    } else {
        int cw = (w - 4) * 32;
        float biasr[2];
        #pragma unroll
        for (int j = 0; j < 2; ++j)
            biasr[j] = bias_kv[HID + cw + j*16 + (l & 15)];
        #pragma unroll
        for (int mt = 0; mt < 4; ++mt) {
            float v0v[4], v1v[4];
            #pragma unroll
            for (int i = 0; i < 4; ++i) {
                int n = mt*16 + ((l >> 4) << 2) + i;
                const float* trow = v_tab + (size_t)nb_lds[n]*HID + cw + (l & 15);
                v0v[i] = trow[0];
                v1v[i] = trow[16];
            }
            #pragma unroll
            for (int i = 0; i < 4; ++i) {
                acc[mt][0][i] += biasr[0] + v0v[i];
                acc[mt][1][i] += biasr[1] + v1v[i];
            }
        }
    }
    __syncthreads();

    // ---- phase 4: scores + softmax. lane l = neighbor l; wave w = head w ----
    {
        const short* krow = &Ksh[l*KST + w*16];
        float s = 0.f;
        #pragma unroll
        for (int e = 0; e < 8; ++e) {
            unsigned u = *(const unsigned*)(&krow[2*e]);
            float k0 = __uint_as_float(u << 16);
            float k1 = __uint_as_float(u & 0xffff0000u);
            s = fmaf(q_lds[w*16 + 2*e],     k0, s);
            s = fmaf(q_lds[w*16 + 2*e + 1], k1, s);
        }
        float sc = s * NORMS + maskadd[l];
        float m = sc;
        #pragma unroll
        for (int off = 1; off <= 32; off <<= 1)
            m = fmaxf(m, __shfl_xor(m, off));
        float e = __expf(sc - m);
        float sum = e;
        #pragma unroll
        for (int off = 1; off <= 32; off <<= 1)
            sum += __shfl_xor(sum, off);
        attn_t[l][w] = e / sum;
    }
    __syncthreads();

    // ---- phase 5: PV in registers (waves 4-7 hold v) + cross-group reduce ----
    if (w >= 4) {
        int g = w - 4;
        float p[2] = {0.f, 0.f};
        #pragma unroll
        for (int mt = 0; mt < 4; ++mt) {
            #pragma unroll
            for (int i = 0; i < 4; ++i) {
                int n = mt*16 + ((l >> 4) << 2) + i;
                f32x2 at = *(const f32x2*)(&attn_t[n][2*g]);
                p[0] = fmaf(at[0], acc[mt][0][i], p[0]);
                p[1] = fmaf(at[1], acc[mt][1][i], p[1]);
            }
        }
        #pragma unroll
        for (int j = 0; j < 2; ++j) {
            p[j] += __shfl_xor(p[j], 16);
            p[j] += __shfl_xor(p[j], 32);
        }
        if (l < 16) {
            #pragma unroll
            for (int j = 0; j < 2; ++j) {
                int col = g*32 + j*16 + l;
                out[(size_t)b*HID + col] = anyvalid ? p[j] : 0.f;
            }
        }
    }
}

extern "C" void kernel_launch(void* const* d_in, const int* in_sizes, int n_in,
                              void* d_out, int out_size, void* d_ws, size_t ws_size,
                              hipStream_t stream)
{
    const float* k_tab = (const float*)d_in[0];
    const float* q_tab = (const float*)d_in[1];
    const float* v_tab = (const float*)d_in[2];
    const int*   nid   = (const int*)d_in[3];
    const int*   neighbors = (const int*)d_in[4];
    const float* times = (const float*)d_in[5];
    const float* rels  = (const float*)d_in[6];
    const float* t2v_w = (const float*)d_in[7];
    const float* t2v_b = (const float*)d_in[8];
    const float* tW_k  = (const float*)d_in[9];
    const float* tb_k  = (const float*)d_in[10];
    const float* tW_q  = (const float*)d_in[11];
    const float* tb_q  = (const float*)d_in[12];
    const float* tW_v  = (const float*)d_in[13];
    const float* tb_v  = (const float*)d_in[14];
    const float* rW_k  = (const float*)d_in[15];
    const float* rb_k  = (const float*)d_in[16];
    const float* rW_v  = (const float*)d_in[17];
    const float* rb_v  = (const float*)d_in[18];

    short* wfrag   = (short*)d_ws;                          // 32768 bf16 = 64KB
    float* bias_kv = (float*)((char*)d_ws + 65536);         // 256 f32
    float* q0_add  = (float*)((char*)d_ws + 65536 + 1024);  // 128 f32

    prep_kernel<<<130, 256, 0, stream>>>(t2v_w, t2v_b, tW_k, tb_k, tW_q, tb_q,
                                         tW_v, tb_v, rW_k, rb_k, rW_v, rb_v,
                                         wfrag, bias_kv, q0_add);
    aggr_kernel<<<BATCH, 512, 0, stream>>>(k_tab, q_tab, v_tab, nid, neighbors,
                                           times, rels, t2v_w, t2v_b,
                                           wfrag, bias_kv, q0_add, (float*)d_out);
}